// Round 4
// baseline (142.951 us; speedup 1.0000x reference)
//
#include <hip/hip_runtime.h>
#include <hip/hip_bf16.h>

// AvgPool2d 2x2 stride 2, no padding.
// x: [32, 256, 128, 128] f32 -> out: [32, 256, 64, 64] f32.
//
// Mapping: one thread per float2 of output (2 adjacent output columns).
// Each thread loads one float4 from input row 2*oh and one from row 2*oh+1
// (contiguous 16B/lane; per half-wave 512B = one full input row), computes
// two averages, stores one float2 (512B/wave contiguous).
//
// n_units = 16,777,216 = GRID(4096) * BLOCK(256) * ITERS(16), exact.
// unroll 8: 16 independent loads in flight before the first vmcnt wait.
// NT on the store stream only (keep L2 clean for reads); plain loads.

typedef float f32x4 __attribute__((ext_vector_type(4)));
typedef float f32x2 __attribute__((ext_vector_type(2)));

#define IN_W   128
#define IN_HW  (128 * 128)

#define GRID   4096
#define BLOCK  256
#define ITERS  16

__global__ __launch_bounds__(BLOCK) void avgpool2x2_kernel(
    const float* __restrict__ in, float* __restrict__ out) {
    const int tid = blockIdx.x * BLOCK + threadIdx.x;
    const int stride = GRID * BLOCK;

#pragma unroll 8
    for (int it = 0; it < ITERS; ++it) {
        int u = tid + it * stride;

        int ow2 = u & 31;            // which float2 within the 64-wide output row
        int rest = u >> 5;
        int oh = rest & 63;
        int img = rest >> 6;         // fused (n, c) index, 0..8191

        const float* src = in + (size_t)img * IN_HW + (size_t)(2 * oh) * IN_W + ow2 * 4;
        f32x4 a = *reinterpret_cast<const f32x4*>(src);
        f32x4 b = *reinterpret_cast<const f32x4*>(src + IN_W);

        f32x2 r;
        r.x = (a.x + a.y + b.x + b.y) * 0.25f;
        r.y = (a.z + a.w + b.z + b.w) * 0.25f;
        __builtin_nontemporal_store(r, reinterpret_cast<f32x2*>(out + (size_t)u * 2));
    }
}

extern "C" void kernel_launch(void* const* d_in, const int* in_sizes, int n_in,
                              void* d_out, int out_size, void* d_ws, size_t ws_size,
                              hipStream_t stream) {
    const float* x = (const float*)d_in[0];
    float* out = (float*)d_out;

    // out_size = 32*256*64*64 = 33,554,432 -> 16,777,216 float2 units,
    // exactly GRID*BLOCK*ITERS.
    avgpool2x2_kernel<<<GRID, BLOCK, 0, stream>>>(x, out);
}

// Round 5
// 113.889 us; speedup vs baseline: 1.2552x; 1.2552x over previous
//
#include <hip/hip_runtime.h>
#include <hip/hip_bf16.h>

// AvgPool2d 2x2 stride 2, no padding.
// x: [32, 256, 128, 128] f32 -> out: [32, 256, 64, 64] f32.
//
// Mapping: one thread per float2 of output (2 adjacent output columns).
// Each thread loads one float4 from input row 2*oh and one from row 2*oh+1
// (contiguous 16B/lane), computes two averages, stores one float2.
//
// R3 config (best: 130.6us): NT loads + NT stores, unroll 4 (unroll 8
// regressed -9.5%, likely VGPR/occupancy). This round's single change:
// block-contiguous iteration mapping — each block streams a contiguous
// 4096-unit (32KB out / 128KB in) window instead of striding 8MB per
// iteration, for DRAM page locality.
//
// n_units = 16,777,216 = GRID(4096) * BLOCK(256) * ITERS(16), exact.

typedef float f32x4 __attribute__((ext_vector_type(4)));
typedef float f32x2 __attribute__((ext_vector_type(2)));

#define IN_W   128
#define IN_HW  (128 * 128)

#define GRID   4096
#define BLOCK  256
#define ITERS  16

__global__ __launch_bounds__(BLOCK) void avgpool2x2_kernel(
    const float* __restrict__ in, float* __restrict__ out) {
    const int base = blockIdx.x * (BLOCK * ITERS) + threadIdx.x;

#pragma unroll 4
    for (int it = 0; it < ITERS; ++it) {
        int u = base + it * BLOCK;

        int ow2 = u & 31;            // which float2 within the 64-wide output row
        int rest = u >> 5;
        int oh = rest & 63;
        int img = rest >> 6;         // fused (n, c) index, 0..8191

        const float* src = in + (size_t)img * IN_HW + (size_t)(2 * oh) * IN_W + ow2 * 4;
        f32x4 a = __builtin_nontemporal_load(reinterpret_cast<const f32x4*>(src));
        f32x4 b = __builtin_nontemporal_load(reinterpret_cast<const f32x4*>(src + IN_W));

        f32x2 r;
        r.x = (a.x + a.y + b.x + b.y) * 0.25f;
        r.y = (a.z + a.w + b.z + b.w) * 0.25f;
        __builtin_nontemporal_store(r, reinterpret_cast<f32x2*>(out + (size_t)u * 2));
    }
}

extern "C" void kernel_launch(void* const* d_in, const int* in_sizes, int n_in,
                              void* d_out, int out_size, void* d_ws, size_t ws_size,
                              hipStream_t stream) {
    const float* x = (const float*)d_in[0];
    float* out = (float*)d_out;

    // out_size = 32*256*64*64 = 33,554,432 -> 16,777,216 float2 units,
    // exactly GRID*BLOCK*ITERS.
    avgpool2x2_kernel<<<GRID, BLOCK, 0, stream>>>(x, out);
}